// Round 6
// baseline (144.849 us; speedup 1.0000x reference)
//
#include <hip/hip_runtime.h>
#include <math.h>

// Problem constants: B=8, L=2048, T=512, Dh=1024, Dg=768, Dp=256, SCALE=Dp^-0.5
#define BATCH 8
#define LKEYS 2048
#define TQ    512
#define DH    1024
#define DG    768
#define DP    256
#define SCALE 0.0625f

typedef short  short8  __attribute__((ext_vector_type(8)));   // MFMA A/B frag (8 bf16)
typedef float  floatx4 __attribute__((ext_vector_type(4)));   // MFMA C/D frag
typedef unsigned short u16x4 __attribute__((ext_vector_type(4)));
typedef unsigned short u16x8 __attribute__((ext_vector_type(8)));

typedef unsigned int __attribute__((address_space(1))) as1_uint;
typedef unsigned int __attribute__((address_space(3))) as3_uint;

__device__ __forceinline__ unsigned short f2b(float f) {
    union { float f; unsigned int u; } v; v.f = f;
    unsigned int u = v.u;
    unsigned int r = u + 0x7fffu + ((u >> 16) & 1u);   // RNE
    if ((u & 0x7f800000u) == 0x7f800000u) r = u;        // inf/nan passthrough
    return (unsigned short)(r >> 16);
}

// async global->LDS, 16B per lane (lane-linear LDS dest).
__device__ __forceinline__ void gload_lds16(const void* g, void* l) {
    __builtin_amdgcn_global_load_lds((const as1_uint*)g, (as3_uint*)l, 16, 0, 0);
}

// s_waitcnt immediate: vmcnt=vm (<=15), expcnt/lgkmcnt = max (don't wait)
__host__ __device__ constexpr int wcnt_vm(int vm) {
    return (vm & 15) | (7 << 4) | (15 << 8);
}

// ---------------------------------------------------------------------------
// Pipelined all-bf16 MFMA GEMM: BM x BN tile, 4 waves (2x2), BK=32,
// 4 LDS buffers, prefetch DEPTH 3, stage-AFTER-barrier (race-free with 4
// buffers: reads of buf t-1 are lgkm-complete before each wave reaches
// barrier_t; the write to that buf is issued only after barrier_t).
// Counted vmcnt (never 0 in steady state), setprio around MFMA.
//   OMODE: 0 = C fp32, 1 = C bf16, 2 = C fp32 with scale + key-mask
//   SWZ:   XCD-chunked (bx,by) swizzle (needs gx*gy % 8 == 0)
//   KSPLIT: 2 => blockIdx.z = half*8 + batch, K arg is per-split K,
//           C += half*sP (fp32 partials, reduced by reduce_add)
// A row-major bf16 [M][lda]; B N-major bf16 [N][ldb] (row n = B^T[n][:]).
// ---------------------------------------------------------------------------
template<int BM, int BN, int OMODE, int SWZ, int KSPLIT>
__global__ __launch_bounds__(256) void gemm_bf16_p(
    const unsigned short* __restrict__ Ap, const unsigned short* __restrict__ Bp,
    const int* __restrict__ maskp, void* __restrict__ Cp,
    int K, int lda, int ldb, int ldc,
    long sA, long sB, long sC, long sM, long sP, float scale)
{
    constexpr int FM = BM / 32, FN = BN / 32;
    constexpr int AI = BM / 64, BI = BN / 64;
    constexpr int NL = AI + BI;                 // gload_lds instrs per tile per thread

    __shared__ unsigned short As[4][BM * 32];
    __shared__ unsigned short Bs[4][BN * 32];

    int bx = blockIdx.x, by = blockIdx.y;
    if (SWZ) {
        const int gx = gridDim.x;
        const int nwg = gx * gridDim.y;         // % 8 == 0
        const int f = by * gx + bx;
        const int nper = nwg >> 3;
        const int fl = (f & 7) * nper + (f >> 3);
        bx = fl % gx; by = fl / gx;
    }
    const int zz   = blockIdx.z;
    const int z    = (KSPLIT == 2) ? (zz & 7) : zz;     // batch
    const int half = (KSPLIT == 2) ? (zz >> 3) : 0;     // K-split half
    const int koff = half * K;

    const int tid  = threadIdx.x;
    const int lane = tid & 63;
    const int wid  = tid >> 6;
    const int wr   = wid >> 1, wc = wid & 1;
    const int lrow = lane & 15;
    const int g    = lane >> 4;

    const unsigned short* A = Ap + (long)z * sA + (long)(by * BM) * lda + koff;
    const unsigned short* B = Bp + (long)z * sB + (long)(bx * BN) * ldb + koff;
    const int srow = tid >> 2, sslot = tid & 3;

    const int nt = K / 32;
    floatx4 acc[FM][FN] = {};

    auto stage = [&](int t, int b) {
        const int k0 = t * 32;
        #pragma unroll
        for (int i = 0; i < AI; ++i)
            gload_lds16(A + (long)(srow + i * 64) * lda + k0 + sslot * 8,
                        (void*)&As[b][(i * 256 + tid) * 8]);
        #pragma unroll
        for (int i = 0; i < BI; ++i)
            gload_lds16(B + (long)(srow + i * 64) * ldb + k0 + sslot * 8,
                        (void*)&Bs[b][(i * 256 + tid) * 8]);
    };

    stage(0, 0);
    stage(1, 1);
    stage(2, 2);
    for (int t = 0; t < nt; ++t) {
        // my tile-t loads landed (in-order vmcnt retire):
        if (t < nt - 2)      __builtin_amdgcn_s_waitcnt(wcnt_vm(2 * NL));
        else if (t == nt - 2) __builtin_amdgcn_s_waitcnt(wcnt_vm(NL));
        else                  __builtin_amdgcn_s_waitcnt(wcnt_vm(0));
        __builtin_amdgcn_s_barrier();            // all waves' tile t landed
        __builtin_amdgcn_sched_barrier(0);
        if (t + 3 < nt) stage(t + 3, (t + 3) & 3);   // overwrites buf (t-1)&3: safe post-barrier
        __builtin_amdgcn_sched_barrier(0);

        const int b = t & 3;
        short8 a[FM], bf[FN];
        #pragma unroll
        for (int m = 0; m < FM; ++m)
            a[m] = *(const short8*)&As[b][(wr * (BM / 2) + m * 16 + lrow) * 32 + g * 8];
        #pragma unroll
        for (int n = 0; n < FN; ++n)
            bf[n] = *(const short8*)&Bs[b][(wc * (BN / 2) + n * 16 + lrow) * 32 + g * 8];
        __builtin_amdgcn_s_setprio(1);
        #pragma unroll
        for (int m = 0; m < FM; ++m)
            #pragma unroll
            for (int n = 0; n < FN; ++n)
                acc[m][n] = __builtin_amdgcn_mfma_f32_16x16x32_bf16(
                    a[m], bf[n], acc[m][n], 0, 0, 0);
        __builtin_amdgcn_s_setprio(0);
        __builtin_amdgcn_sched_barrier(0);
    }

    // ---- epilogue: D row = 4g + reg, col = lrow (m89-verified layout) ----
    const int orow = by * BM + wr * (BM / 2);
    const int ocol = bx * BN + wc * (BN / 2);
    if (OMODE == 0) {
        float* C = (float*)Cp + (long)z * sC + (long)half * sP;
        #pragma unroll
        for (int m = 0; m < FM; ++m)
            #pragma unroll
            for (int n = 0; n < FN; ++n)
                #pragma unroll
                for (int r = 0; r < 4; ++r)
                    C[(long)(orow + m * 16 + 4 * g + r) * ldc + ocol + n * 16 + lrow]
                        = acc[m][n][r];
    } else if (OMODE == 1) {
        unsigned short* C = (unsigned short*)Cp + (long)z * sC;
        #pragma unroll
        for (int m = 0; m < FM; ++m)
            #pragma unroll
            for (int n = 0; n < FN; ++n)
                #pragma unroll
                for (int r = 0; r < 4; ++r)
                    C[(long)(orow + m * 16 + 4 * g + r) * ldc + ocol + n * 16 + lrow]
                        = f2b(acc[m][n][r]);
    } else {
        const int* mask = maskp + (long)z * sM;
        float* C = (float*)Cp + (long)z * sC;
        #pragma unroll
        for (int n = 0; n < FN; ++n) {
            int c = ocol + n * 16 + lrow;
            bool masked = (mask[c] != 0);
            #pragma unroll
            for (int m = 0; m < FM; ++m)
                #pragma unroll
                for (int r = 0; r < 4; ++r)
                    C[(long)(orow + m * 16 + 4 * g + r) * ldc + c]
                        = masked ? -INFINITY : acc[m][n][r] * scale;
        }
    }
}

// ---------------------------------------------------------------------------
// Z = P0 + P1 (split-K reduce), float4-wide.
// ---------------------------------------------------------------------------
__global__ __launch_bounds__(256) void reduce_add(
    const float4* __restrict__ P0, const float4* __restrict__ P1,
    float4* __restrict__ Zo)
{
    long i = (long)blockIdx.x * 256 + threadIdx.x;
    float4 a = P0[i], b = P1[i];
    Zo[i] = make_float4(a.x + b.x, a.y + b.y, a.z + b.z, a.w + b.w);
}

// ---------------------------------------------------------------------------
// Weight transpose + convert: W [D][P] fp32 -> WT [P][D] bf16.
// ---------------------------------------------------------------------------
__global__ __launch_bounds__(256) void transpose_w(
    const float* __restrict__ W, unsigned short* __restrict__ WT, int D, int P)
{
    __shared__ float t[32][33];
    const int d0 = blockIdx.x * 32, p0 = blockIdx.y * 32;
    const int tx = threadIdx.x & 31, ty = threadIdx.x >> 5;   // 32x8
    #pragma unroll
    for (int j = 0; j < 4; ++j)
        t[ty + 8 * j][tx] = W[(long)(d0 + ty + 8 * j) * P + p0 + tx];
    __syncthreads();
    #pragma unroll
    for (int j = 0; j < 4; ++j)
        WT[(long)(p0 + ty + 8 * j) * D + d0 + tx] = f2b(t[tx][ty + 8 * j]);
}

// ---------------------------------------------------------------------------
// H [B,L,Dh] fp32 -> Hb [B,L,Dh] bf16 AND HbT [B,Dh,L] bf16, one read.
// ---------------------------------------------------------------------------
__global__ __launch_bounds__(256) void prep_H(
    const float* __restrict__ H, unsigned short* __restrict__ Hb,
    unsigned short* __restrict__ HbT)
{
    __shared__ float tf[32][33];
    const int z = blockIdx.z;
    const int d0 = blockIdx.x * 32, l0 = blockIdx.y * 32;
    const float* Hz = H + (long)z * LKEYS * DH;
    unsigned short* Hbz = Hb + (long)z * LKEYS * DH;
    unsigned short* Tz = HbT + (long)z * DH * LKEYS;
    const int r = threadIdx.x >> 3, c = threadIdx.x & 7;
    float4 v = *(const float4*)&Hz[(long)(l0 + r) * DH + d0 + 4 * c];
    u16x4 w;
    w[0] = f2b(v.x); w[1] = f2b(v.y); w[2] = f2b(v.z); w[3] = f2b(v.w);
    *(u16x4*)&Hbz[(long)(l0 + r) * DH + d0 + 4 * c] = w;
    tf[r][4 * c + 0] = v.x; tf[r][4 * c + 1] = v.y;
    tf[r][4 * c + 2] = v.z; tf[r][4 * c + 3] = v.w;
    __syncthreads();
    u16x4 o;
    o[0] = f2b(tf[4 * c + 0][r]); o[1] = f2b(tf[4 * c + 1][r]);
    o[2] = f2b(tf[4 * c + 2][r]); o[3] = f2b(tf[4 * c + 3][r]);
    *(u16x4*)&Tz[(long)(d0 + r) * LKEYS + l0 + 4 * c] = o;
}

// G fp32 -> Gb bf16, streaming.
__global__ __launch_bounds__(256) void prep_G(
    const float* __restrict__ G, unsigned short* __restrict__ Gb)
{
    long i = ((long)blockIdx.x * 256 + threadIdx.x) * 8;
    float4 a = *(const float4*)&G[i];
    float4 b = *(const float4*)&G[i + 4];
    u16x8 w;
    w[0] = f2b(a.x); w[1] = f2b(a.y); w[2] = f2b(a.z); w[3] = f2b(a.w);
    w[4] = f2b(b.x); w[5] = f2b(b.y); w[6] = f2b(b.z); w[7] = f2b(b.w);
    *(u16x8*)&Gb[i] = w;
}

// ---------------------------------------------------------------------------
// Row softmax, register-cached: 2048 floats/row, 8 elems/thread.
// ---------------------------------------------------------------------------
__global__ __launch_bounds__(256) void softmax_kernel(
    const float* __restrict__ S, unsigned short* __restrict__ Ab)
{
    const float4* row4 = (const float4*)(S + (long)blockIdx.x * LKEYS);
    u16x4* out4 = (u16x4*)(Ab + (long)blockIdx.x * LKEYS);
    const int tid = threadIdx.x;
    __shared__ float red[4];

    float4 v0 = row4[tid], v1 = row4[tid + 256];
    float m = fmaxf(fmaxf(fmaxf(v0.x, v0.y), fmaxf(v0.z, v0.w)),
                    fmaxf(fmaxf(v1.x, v1.y), fmaxf(v1.z, v1.w)));
    #pragma unroll
    for (int off = 32; off > 0; off >>= 1) m = fmaxf(m, __shfl_xor(m, off));
    if ((tid & 63) == 0) red[tid >> 6] = m;
    __syncthreads();
    m = fmaxf(fmaxf(red[0], red[1]), fmaxf(red[2], red[3]));

    float e[8];
    e[0] = __expf(v0.x - m); e[1] = __expf(v0.y - m);
    e[2] = __expf(v0.z - m); e[3] = __expf(v0.w - m);
    e[4] = __expf(v1.x - m); e[5] = __expf(v1.y - m);
    e[6] = __expf(v1.z - m); e[7] = __expf(v1.w - m);
    float s = ((e[0] + e[1]) + (e[2] + e[3])) + ((e[4] + e[5]) + (e[6] + e[7]));
    #pragma unroll
    for (int off = 32; off > 0; off >>= 1) s += __shfl_xor(s, off);
    __syncthreads();
    if ((tid & 63) == 0) red[tid >> 6] = s;
    __syncthreads();
    s = red[0] + red[1] + red[2] + red[3];

    float inv = 1.0f / s;
    u16x4 a0, a1;
    a0[0] = f2b(e[0] * inv); a0[1] = f2b(e[1] * inv);
    a0[2] = f2b(e[2] * inv); a0[3] = f2b(e[3] * inv);
    a1[0] = f2b(e[4] * inv); a1[1] = f2b(e[5] * inv);
    a1[2] = f2b(e[6] * inv); a1[3] = f2b(e[7] * inv);
    out4[tid] = a0; out4[tid + 256] = a1;
}

// ---------------------------------------------------------------------------
extern "C" void kernel_launch(void* const* d_in, const int* in_sizes, int n_in,
                              void* d_out, int out_size, void* d_ws, size_t ws_size,
                              hipStream_t stream)
{
    const float* H    = (const float*)d_in[0];  // [B,L,Dh]
    const float* G    = (const float*)d_in[1];  // [B,T,Dg]
    const int*   mask = (const int*)  d_in[2];  // [B,L]
    const float* Wk   = (const float*)d_in[3];  // [Dh,Dp]
    const float* Wq   = (const float*)d_in[4];  // [Dg,Dp]
    float*       Z    = (float*)d_out;          // [B,T,Dh]

    // Workspace (101.6 MB, verified fits in R5). u16 offsets:
    // WkT|WqT|Ab|Kb|Qb|Gb|HbT|X  where X = Hb (pre-softmax) then S (logits)
    // then Zp partials (post-softmax) — all 33.5 MB, serially dead.
    unsigned short* WkT = (unsigned short*)d_ws;      // 256*1024
    unsigned short* WqT = WkT + 262144;               // 256*768
    unsigned short* Ab  = WqT + 196608;               // 8*512*2048 bf16
    unsigned short* Kb  = Ab  + 8388608;              // 8*2048*256
    unsigned short* Qb  = Kb  + 4194304;              // 8*512*256
    unsigned short* Gb  = Qb  + 1048576;              // 8*512*768
    unsigned short* HbT = Gb  + 3145728;              // 8*1024*2048
    unsigned short* Hb  = HbT + 16777216;             // 8*2048*1024
    float*          S   = (float*)Hb;                 // overlays Hb
    float*          Zp  = (float*)Hb;                 // overlays S: 2*8*512*1024 f32

    transpose_w<<<dim3(DH / 32, DP / 32), 256, 0, stream>>>(Wk, WkT, DH, DP);
    transpose_w<<<dim3(DG / 32, DP / 32), 256, 0, stream>>>(Wq, WqT, DG, DP);

    prep_G<<<1536, 256, 0, stream>>>(G, Gb);
    prep_H<<<dim3(DH / 32, LKEYS / 32, BATCH), 256, 0, stream>>>(H, Hb, HbT);

    // K = Hb @ WkT^T : M=16384, N=256, K=1024 -> Kb bf16. 512 blocks, depth-3.
    gemm_bf16_p<128, 64, 1, 1, 1><<<dim3(4, 128, 1), 256, 0, stream>>>(
        Hb, WkT, nullptr, Kb, DH, DH, DH, DP, 0, 0, 0, 0, 0, 1.f);

    // Q = Gb @ WqT^T : M=4096, N=256, K=768 -> Qb bf16. 256 blocks.
    gemm_bf16_p<64, 64, 1, 1, 1><<<dim3(4, 64, 1), 256, 0, stream>>>(
        Gb, WqT, nullptr, Qb, DG, DG, DG, DP, 0, 0, 0, 0, 0, 1.f);

    // logits = scale * Qb @ Kb^T, masked : per batch 512x2048x256 -> S fp32. 1024 blocks.
    gemm_bf16_p<128, 64, 2, 1, 1><<<dim3(32, 4, BATCH), 256, 0, stream>>>(
        Qb, Kb, mask, S, DP, DP, DP, LKEYS,
        (long)TQ * DP, (long)LKEYS * DP, (long)TQ * LKEYS, (long)LKEYS, 0, SCALE);

    // softmax over L -> bf16 alpha (S dead after this; Zp overlays it)
    softmax_kernel<<<BATCH * TQ, 256, 0, stream>>>(S, Ab);

    // Z partials = Ab @ HbT^T, split-K x2 : per (batch,half) 512x1024x1024.
    // 1024 blocks -> 3 blocks/CU (48 KB LDS), 12 waves/CU.
    gemm_bf16_p<128, 64, 0, 1, 2><<<dim3(16, 4, 2 * BATCH), 256, 0, stream>>>(
        Ab, HbT, nullptr, Zp, LKEYS / 2, LKEYS, LKEYS, DH,
        (long)TQ * LKEYS, (long)DH * LKEYS, (long)TQ * DH, 0,
        (long)BATCH * TQ * DH, 1.f);

    // Z = Zp[0] + Zp[1]
    reduce_add<<<(BATCH * TQ * DH / 4) / 256, 256, 0, stream>>>(
        (const float4*)Zp, (const float4*)(Zp + (long)BATCH * TQ * DH),
        (float4*)Z);
}

// Round 7
// 127.912 us; speedup vs baseline: 1.1324x; 1.1324x over previous
//
#include <hip/hip_runtime.h>
#include <math.h>

// Problem constants: B=8, L=2048, T=512, Dh=1024, Dg=768, Dp=256, SCALE=Dp^-0.5
#define BATCH 8
#define LKEYS 2048
#define TQ    512
#define DH    1024
#define DG    768
#define DP    256
#define SCALE 0.0625f

typedef short  short8  __attribute__((ext_vector_type(8)));   // MFMA A/B frag (8 bf16)
typedef float  floatx4 __attribute__((ext_vector_type(4)));   // MFMA C/D frag
typedef unsigned short u16x4 __attribute__((ext_vector_type(4)));
typedef unsigned short u16x8 __attribute__((ext_vector_type(8)));

typedef unsigned int __attribute__((address_space(1))) as1_uint;
typedef unsigned int __attribute__((address_space(3))) as3_uint;

__device__ __forceinline__ unsigned short f2b(float f) {
    union { float f; unsigned int u; } v; v.f = f;
    unsigned int u = v.u;
    unsigned int r = u + 0x7fffu + ((u >> 16) & 1u);   // RNE
    if ((u & 0x7f800000u) == 0x7f800000u) r = u;        // inf/nan passthrough
    return (unsigned short)(r >> 16);
}

// async global->LDS, 16B per lane (lane-linear LDS dest).
__device__ __forceinline__ void gload_lds16(const void* g, void* l) {
    __builtin_amdgcn_global_load_lds((const as1_uint*)g, (as3_uint*)l, 16, 0, 0);
}

// s_waitcnt immediate: vmcnt=vm (<=15), expcnt/lgkmcnt = max (don't wait)
__host__ __device__ constexpr int wcnt_vm(int vm) {
    return (vm & 15) | (7 << 4) | (15 << 8);
}

// ---------------------------------------------------------------------------
// Pipelined all-bf16 MFMA GEMM: BM x BN tile, 4 waves (2x2), BK=32,
// 4 LDS buffers, prefetch depth 2, R5 ordering: stage(t+2) -> counted
// vmcnt (never 0 in steady state) -> s_barrier -> ds_read/MFMA (setprio).
// Wave tile (BM/2)x(BN/2); 64x64 wave tile = 32.8 F/B (LDS-balanced).
//   OMODE: 0 = C fp32, 1 = C bf16, 2 = C fp32 with scale + key-mask
//   SWZ:   XCD-chunked (bx,by) swizzle (needs gx*gy % 8 == 0)
//   KSPLIT: 2 => blockIdx.z = half*8 + batch, K arg = per-split K,
//           C += half*sP (fp32 partials, summed by reduce_add)
// A row-major bf16 [M][lda]; B N-major bf16 [N][ldb] (row n = B^T[n][:]).
// ---------------------------------------------------------------------------
template<int BM, int BN, int OMODE, int SWZ, int KSPLIT>
__global__ __launch_bounds__(256) void gemm_bf16_p(
    const unsigned short* __restrict__ Ap, const unsigned short* __restrict__ Bp,
    const int* __restrict__ maskp, void* __restrict__ Cp,
    int K, int lda, int ldb, int ldc,
    long sA, long sB, long sC, long sM, long sP, float scale)
{
    constexpr int FM = BM / 32, FN = BN / 32;
    constexpr int AI = BM / 64, BI = BN / 64;
    constexpr int NL = AI + BI;                 // gload_lds instrs per tile per thread

    __shared__ unsigned short As[4][BM * 32];
    __shared__ unsigned short Bs[4][BN * 32];

    int bx = blockIdx.x, by = blockIdx.y;
    if (SWZ) {
        const int gx = gridDim.x;
        const int nwg = gx * gridDim.y;         // % 8 == 0
        const int f = by * gx + bx;
        const int nper = nwg >> 3;
        const int fl = (f & 7) * nper + (f >> 3);
        bx = fl % gx; by = fl / gx;
    }
    const int zz   = blockIdx.z;
    const int z    = (KSPLIT == 2) ? (zz & 7) : zz;     // batch
    const int half = (KSPLIT == 2) ? (zz >> 3) : 0;     // K-split half
    const int koff = half * K;

    const int tid  = threadIdx.x;
    const int lane = tid & 63;
    const int wid  = tid >> 6;
    const int wr   = wid >> 1, wc = wid & 1;
    const int lrow = lane & 15;
    const int g    = lane >> 4;

    const unsigned short* A = Ap + (long)z * sA + (long)(by * BM) * lda + koff;
    const unsigned short* B = Bp + (long)z * sB + (long)(bx * BN) * ldb + koff;
    const int srow = tid >> 2, sslot = tid & 3;

    const int nt = K / 32;
    floatx4 acc[FM][FN] = {};

    auto stage = [&](int t, int b) {
        const int k0 = t * 32;
        #pragma unroll
        for (int i = 0; i < AI; ++i)
            gload_lds16(A + (long)(srow + i * 64) * lda + k0 + sslot * 8,
                        (void*)&As[b][(i * 256 + tid) * 8]);
        #pragma unroll
        for (int i = 0; i < BI; ++i)
            gload_lds16(B + (long)(srow + i * 64) * ldb + k0 + sslot * 8,
                        (void*)&Bs[b][(i * 256 + tid) * 8]);
    };

    stage(0, 0);
    stage(1, 1);
    for (int t = 0; t < nt; ++t) {
        if (t + 2 < nt) {
            stage(t + 2, (t + 2) & 3);
            __builtin_amdgcn_s_waitcnt(wcnt_vm(2 * NL));   // my tile-t loads landed
        } else if (t + 1 < nt) {
            __builtin_amdgcn_s_waitcnt(wcnt_vm(NL));
        } else {
            __builtin_amdgcn_s_waitcnt(wcnt_vm(0));
        }
        __builtin_amdgcn_s_barrier();                      // all waves' tile t landed
        __builtin_amdgcn_sched_barrier(0);

        const int b = t & 3;
        short8 a[FM], bf[FN];
        #pragma unroll
        for (int m = 0; m < FM; ++m)
            a[m] = *(const short8*)&As[b][(wr * (BM / 2) + m * 16 + lrow) * 32 + g * 8];
        #pragma unroll
        for (int n = 0; n < FN; ++n)
            bf[n] = *(const short8*)&Bs[b][(wc * (BN / 2) + n * 16 + lrow) * 32 + g * 8];
        __builtin_amdgcn_s_setprio(1);
        #pragma unroll
        for (int m = 0; m < FM; ++m)
            #pragma unroll
            for (int n = 0; n < FN; ++n)
                acc[m][n] = __builtin_amdgcn_mfma_f32_16x16x32_bf16(
                    a[m], bf[n], acc[m][n], 0, 0, 0);
        __builtin_amdgcn_s_setprio(0);
        __builtin_amdgcn_sched_barrier(0);
    }

    // ---- epilogue: D row = 4g + reg, col = lrow (m89-verified layout) ----
    const int orow = by * BM + wr * (BM / 2);
    const int ocol = bx * BN + wc * (BN / 2);
    if (OMODE == 0) {
        float* C = (float*)Cp + (long)z * sC + (long)half * sP;
        #pragma unroll
        for (int m = 0; m < FM; ++m)
            #pragma unroll
            for (int n = 0; n < FN; ++n)
                #pragma unroll
                for (int r = 0; r < 4; ++r)
                    C[(long)(orow + m * 16 + 4 * g + r) * ldc + ocol + n * 16 + lrow]
                        = acc[m][n][r];
    } else if (OMODE == 1) {
        unsigned short* C = (unsigned short*)Cp + (long)z * sC;
        #pragma unroll
        for (int m = 0; m < FM; ++m)
            #pragma unroll
            for (int n = 0; n < FN; ++n)
                #pragma unroll
                for (int r = 0; r < 4; ++r)
                    C[(long)(orow + m * 16 + 4 * g + r) * ldc + ocol + n * 16 + lrow]
                        = f2b(acc[m][n][r]);
    } else {
        const int* mask = maskp + (long)z * sM;
        float* C = (float*)Cp + (long)z * sC;
        #pragma unroll
        for (int n = 0; n < FN; ++n) {
            int c = ocol + n * 16 + lrow;
            bool masked = (mask[c] != 0);
            #pragma unroll
            for (int m = 0; m < FM; ++m)
                #pragma unroll
                for (int r = 0; r < 4; ++r)
                    C[(long)(orow + m * 16 + 4 * g + r) * ldc + c]
                        = masked ? -INFINITY : acc[m][n][r] * scale;
        }
    }
}

// ---------------------------------------------------------------------------
// Z = P0 + P1 (split-K reduce), float4-wide.
// ---------------------------------------------------------------------------
__global__ __launch_bounds__(256) void reduce_add(
    const float4* __restrict__ P0, const float4* __restrict__ P1,
    float4* __restrict__ Zo)
{
    long i = (long)blockIdx.x * 256 + threadIdx.x;
    float4 a = P0[i], b = P1[i];
    Zo[i] = make_float4(a.x + b.x, a.y + b.y, a.z + b.z, a.w + b.w);
}

// ---------------------------------------------------------------------------
// Weight transpose + convert: W [D][P] fp32 -> WT [P][D] bf16.
// ---------------------------------------------------------------------------
__global__ __launch_bounds__(256) void transpose_w(
    const float* __restrict__ W, unsigned short* __restrict__ WT, int D, int P)
{
    __shared__ float t[32][33];
    const int d0 = blockIdx.x * 32, p0 = blockIdx.y * 32;
    const int tx = threadIdx.x & 31, ty = threadIdx.x >> 5;   // 32x8
    #pragma unroll
    for (int j = 0; j < 4; ++j)
        t[ty + 8 * j][tx] = W[(long)(d0 + ty + 8 * j) * P + p0 + tx];
    __syncthreads();
    #pragma unroll
    for (int j = 0; j < 4; ++j)
        WT[(long)(p0 + ty + 8 * j) * D + d0 + tx] = f2b(t[tx][ty + 8 * j]);
}

// ---------------------------------------------------------------------------
// H [B,L,Dh] fp32 -> Hb [B,L,Dh] bf16 AND HbT [B,Dh,L] bf16, one read.
// ---------------------------------------------------------------------------
__global__ __launch_bounds__(256) void prep_H(
    const float* __restrict__ H, unsigned short* __restrict__ Hb,
    unsigned short* __restrict__ HbT)
{
    __shared__ float tf[32][33];
    const int z = blockIdx.z;
    const int d0 = blockIdx.x * 32, l0 = blockIdx.y * 32;
    const float* Hz = H + (long)z * LKEYS * DH;
    unsigned short* Hbz = Hb + (long)z * LKEYS * DH;
    unsigned short* Tz = HbT + (long)z * DH * LKEYS;
    const int r = threadIdx.x >> 3, c = threadIdx.x & 7;
    float4 v = *(const float4*)&Hz[(long)(l0 + r) * DH + d0 + 4 * c];
    u16x4 w;
    w[0] = f2b(v.x); w[1] = f2b(v.y); w[2] = f2b(v.z); w[3] = f2b(v.w);
    *(u16x4*)&Hbz[(long)(l0 + r) * DH + d0 + 4 * c] = w;
    tf[r][4 * c + 0] = v.x; tf[r][4 * c + 1] = v.y;
    tf[r][4 * c + 2] = v.z; tf[r][4 * c + 3] = v.w;
    __syncthreads();
    u16x4 o;
    o[0] = f2b(tf[4 * c + 0][r]); o[1] = f2b(tf[4 * c + 1][r]);
    o[2] = f2b(tf[4 * c + 2][r]); o[3] = f2b(tf[4 * c + 3][r]);
    *(u16x4*)&Tz[(long)(d0 + r) * LKEYS + l0 + 4 * c] = o;
}

// G fp32 -> Gb bf16, streaming.
__global__ __launch_bounds__(256) void prep_G(
    const float* __restrict__ G, unsigned short* __restrict__ Gb)
{
    long i = ((long)blockIdx.x * 256 + threadIdx.x) * 8;
    float4 a = *(const float4*)&G[i];
    float4 b = *(const float4*)&G[i + 4];
    u16x8 w;
    w[0] = f2b(a.x); w[1] = f2b(a.y); w[2] = f2b(a.z); w[3] = f2b(a.w);
    w[4] = f2b(b.x); w[5] = f2b(b.y); w[6] = f2b(b.z); w[7] = f2b(b.w);
    *(u16x8*)&Gb[i] = w;
}

// ---------------------------------------------------------------------------
// Row softmax, register-cached: 2048 floats/row, 8 elems/thread.
// ---------------------------------------------------------------------------
__global__ __launch_bounds__(256) void softmax_kernel(
    const float* __restrict__ S, unsigned short* __restrict__ Ab)
{
    const float4* row4 = (const float4*)(S + (long)blockIdx.x * LKEYS);
    u16x4* out4 = (u16x4*)(Ab + (long)blockIdx.x * LKEYS);
    const int tid = threadIdx.x;
    __shared__ float red[4];

    float4 v0 = row4[tid], v1 = row4[tid + 256];
    float m = fmaxf(fmaxf(fmaxf(v0.x, v0.y), fmaxf(v0.z, v0.w)),
                    fmaxf(fmaxf(v1.x, v1.y), fmaxf(v1.z, v1.w)));
    #pragma unroll
    for (int off = 32; off > 0; off >>= 1) m = fmaxf(m, __shfl_xor(m, off));
    if ((tid & 63) == 0) red[tid >> 6] = m;
    __syncthreads();
    m = fmaxf(fmaxf(red[0], red[1]), fmaxf(red[2], red[3]));

    float e[8];
    e[0] = __expf(v0.x - m); e[1] = __expf(v0.y - m);
    e[2] = __expf(v0.z - m); e[3] = __expf(v0.w - m);
    e[4] = __expf(v1.x - m); e[5] = __expf(v1.y - m);
    e[6] = __expf(v1.z - m); e[7] = __expf(v1.w - m);
    float s = ((e[0] + e[1]) + (e[2] + e[3])) + ((e[4] + e[5]) + (e[6] + e[7]));
    #pragma unroll
    for (int off = 32; off > 0; off >>= 1) s += __shfl_xor(s, off);
    __syncthreads();
    if ((tid & 63) == 0) red[tid >> 6] = s;
    __syncthreads();
    s = red[0] + red[1] + red[2] + red[3];

    float inv = 1.0f / s;
    u16x4 a0, a1;
    a0[0] = f2b(e[0] * inv); a0[1] = f2b(e[1] * inv);
    a0[2] = f2b(e[2] * inv); a0[3] = f2b(e[3] * inv);
    a1[0] = f2b(e[4] * inv); a1[1] = f2b(e[5] * inv);
    a1[2] = f2b(e[6] * inv); a1[3] = f2b(e[7] * inv);
    out4[tid] = a0; out4[tid + 256] = a1;
}

// ---------------------------------------------------------------------------
extern "C" void kernel_launch(void* const* d_in, const int* in_sizes, int n_in,
                              void* d_out, int out_size, void* d_ws, size_t ws_size,
                              hipStream_t stream)
{
    const float* H    = (const float*)d_in[0];  // [B,L,Dh]
    const float* G    = (const float*)d_in[1];  // [B,T,Dg]
    const int*   mask = (const int*)  d_in[2];  // [B,L]
    const float* Wk   = (const float*)d_in[3];  // [Dh,Dp]
    const float* Wq   = (const float*)d_in[4];  // [Dg,Dp]
    float*       Z    = (float*)d_out;          // [B,T,Dh]

    // Workspace (101.6 MB). u16 offsets:
    // WkT|WqT|Ab|Kb|Qb|Gb|HbT|X  where X = Hb (pre-softmax) then S (logits)
    // then Zp partials (post-softmax) — 33.5 MB region, serially reused.
    unsigned short* WkT = (unsigned short*)d_ws;      // 256*1024
    unsigned short* WqT = WkT + 262144;               // 256*768
    unsigned short* Ab  = WqT + 196608;               // 8*512*2048 bf16
    unsigned short* Kb  = Ab  + 8388608;              // 8*2048*256
    unsigned short* Qb  = Kb  + 4194304;              // 8*512*256
    unsigned short* Gb  = Qb  + 1048576;              // 8*512*768
    unsigned short* HbT = Gb  + 3145728;              // 8*1024*2048
    unsigned short* Hb  = HbT + 16777216;             // 8*2048*1024
    float*          S   = (float*)Hb;                 // overlays Hb
    float*          Zp  = (float*)Hb;                 // overlays S: 2*8*512*1024 f32

    transpose_w<<<dim3(DH / 32, DP / 32), 256, 0, stream>>>(Wk, WkT, DH, DP);
    transpose_w<<<dim3(DG / 32, DP / 32), 256, 0, stream>>>(Wq, WqT, DG, DP);

    prep_G<<<1536, 256, 0, stream>>>(G, Gb);
    prep_H<<<dim3(DH / 32, LKEYS / 32, BATCH), 256, 0, stream>>>(H, Hb, HbT);

    // K = Hb @ WkT^T : M=16384, N=256, K=1024 -> Kb bf16. 512 blocks, 2/CU.
    gemm_bf16_p<128, 64, 1, 1, 1><<<dim3(4, 128, 1), 256, 0, stream>>>(
        Hb, WkT, nullptr, Kb, DH, DH, DH, DP, 0, 0, 0, 0, 0, 1.f);

    // Q = Gb @ WqT^T : M=4096, N=256, K=768 -> Qb bf16. 256 blocks.
    gemm_bf16_p<64, 64, 1, 1, 1><<<dim3(4, 64, 1), 256, 0, stream>>>(
        Gb, WqT, nullptr, Qb, DG, DG, DG, DP, 0, 0, 0, 0, 0, 1.f);

    // logits = scale * Qb @ Kb^T, masked : per batch 512x2048x256 -> S fp32.
    // 128x128 tile (64x64 wave tiles, 32.8 F/B). 512 blocks, 2/CU.
    gemm_bf16_p<128, 128, 2, 1, 1><<<dim3(16, 4, BATCH), 256, 0, stream>>>(
        Qb, Kb, mask, S, DP, DP, DP, LKEYS,
        (long)TQ * DP, (long)LKEYS * DP, (long)TQ * LKEYS, (long)LKEYS, 0, SCALE);

    // softmax over L -> bf16 alpha (S dead after this; Zp overlays it)
    softmax_kernel<<<BATCH * TQ, 256, 0, stream>>>(S, Ab);

    // Z partials = Ab @ HbT^T, split-K x2, 128x128 tile (64x64 wave tiles):
    // per (batch,half) 512x1024x1024. 512 blocks, 2/CU, 8 waves/CU, 32 iters.
    gemm_bf16_p<128, 128, 0, 1, 2><<<dim3(8, 4, 2 * BATCH), 256, 0, stream>>>(
        Ab, HbT, nullptr, Zp, LKEYS / 2, LKEYS, LKEYS, DH,
        (long)TQ * LKEYS, (long)DH * LKEYS, (long)TQ * DH, 0,
        (long)BATCH * TQ * DH, 1.f);

    // Z = Zp[0] + Zp[1]
    reduce_add<<<(BATCH * TQ * DH / 4) / 256, 256, 0, stream>>>(
        (const float4*)Zp, (const float4*)(Zp + (long)BATCH * TQ * DH),
        (float4*)Z);
}

// Round 8
// 121.186 us; speedup vs baseline: 1.1953x; 1.0555x over previous
//
#include <hip/hip_runtime.h>
#include <math.h>

// Problem constants: B=8, L=2048, T=512, Dh=1024, Dg=768, Dp=256, SCALE=Dp^-0.5
#define BATCH 8
#define LKEYS 2048
#define TQ    512
#define DH    1024
#define DG    768
#define DP    256
#define SCALE 0.0625f

typedef short  short8  __attribute__((ext_vector_type(8)));   // MFMA A/B frag (8 bf16)
typedef float  floatx4 __attribute__((ext_vector_type(4)));   // MFMA C/D frag
typedef unsigned short u16x4 __attribute__((ext_vector_type(4)));
typedef unsigned short u16x8 __attribute__((ext_vector_type(8)));

typedef unsigned int __attribute__((address_space(1))) as1_uint;
typedef unsigned int __attribute__((address_space(3))) as3_uint;

__device__ __forceinline__ unsigned short f2b(float f) {
    union { float f; unsigned int u; } v; v.f = f;
    unsigned int u = v.u;
    unsigned int r = u + 0x7fffu + ((u >> 16) & 1u);   // RNE
    if ((u & 0x7f800000u) == 0x7f800000u) r = u;        // inf/nan passthrough
    return (unsigned short)(r >> 16);
}

// async global->LDS, 16B per lane (lane-linear LDS dest).
__device__ __forceinline__ void gload_lds16(const void* g, void* l) {
    __builtin_amdgcn_global_load_lds((const as1_uint*)g, (as3_uint*)l, 16, 0, 0);
}

// s_waitcnt immediate: vmcnt=vm (<=15), expcnt/lgkmcnt = max (don't wait)
__host__ __device__ constexpr int wcnt_vm(int vm) {
    return (vm & 15) | (7 << 4) | (15 << 8);
}

// ---------------------------------------------------------------------------
// Pipelined all-bf16 MFMA GEMM: BM x BN tile, 4 waves (2x2), BK=32,
// 4 LDS buffers, prefetch depth 2, R5 ordering: stage(t+2) -> counted
// vmcnt (never 0 in steady state) -> s_barrier -> ds_read/MFMA (setprio).
//   OMODE: 0 = C fp32, 1 = C bf16, 2 = C fp32 with scale + key-mask
//   SWZ:   1 = 2D XCD chunk swizzle (z ignored; needs gx*gy % 8 == 0)
//          2 = 3D batched swizzle: XCD owns whole z-slices (needs gz % 8 == 0).
//              HW xcd = linear_id % 8; we remap so xcd k runs zz = k + 8q.
//              Per-XCD working set = one batch's operands -> L2-resident.
//   KSPLIT: 2 => zz = half*8 + batch, K arg = per-split K,
//           C += half*sP (fp32 partials, summed by reduce_add)
// A row-major bf16 [M][lda]; B N-major bf16 [N][ldb] (row n = B^T[n][:]).
// ---------------------------------------------------------------------------
template<int BM, int BN, int OMODE, int SWZ, int KSPLIT>
__global__ __launch_bounds__(256) void gemm_bf16_p(
    const unsigned short* __restrict__ Ap, const unsigned short* __restrict__ Bp,
    const int* __restrict__ maskp, void* __restrict__ Cp,
    int K, int lda, int ldb, int ldc,
    long sA, long sB, long sC, long sM, long sP, float scale)
{
    constexpr int FM = BM / 32, FN = BN / 32;
    constexpr int AI = BM / 64, BI = BN / 64;
    constexpr int NL = AI + BI;                 // gload_lds instrs per tile per thread

    __shared__ unsigned short As[4][BM * 32];
    __shared__ unsigned short Bs[4][BN * 32];

    int bx = blockIdx.x, by = blockIdx.y, zz = blockIdx.z;
    if (SWZ == 1) {
        const int gx = gridDim.x;
        const int nwg = gx * gridDim.y;         // % 8 == 0
        const int f = by * gx + bx;
        const int nper = nwg >> 3;
        const int fl = (f & 7) * nper + (f >> 3);
        bx = fl % gx; by = fl / gx;
    } else if (SWZ == 2) {
        const int gx = gridDim.x, nxy = gridDim.x * gridDim.y;
        const long l = blockIdx.x + (long)gx * (blockIdx.y + (long)gridDim.y * blockIdx.z);
        const int xcd  = (int)(l & 7);
        const int slot = (int)(l >> 3);
        zz = xcd + 8 * (slot / nxy);            // whole z-slices per XCD
        const int rem = slot % nxy;
        bx = rem % gx; by = rem / gx;
    }
    const int z    = (KSPLIT == 2) ? (zz & 7) : zz;     // batch
    const int half = (KSPLIT == 2) ? (zz >> 3) : 0;     // K-split half
    const int koff = half * K;

    const int tid  = threadIdx.x;
    const int lane = tid & 63;
    const int wid  = tid >> 6;
    const int wr   = wid >> 1, wc = wid & 1;
    const int lrow = lane & 15;
    const int g    = lane >> 4;

    const unsigned short* A = Ap + (long)z * sA + (long)(by * BM) * lda + koff;
    const unsigned short* B = Bp + (long)z * sB + (long)(bx * BN) * ldb + koff;
    const int srow = tid >> 2, sslot = tid & 3;

    const int nt = K / 32;
    floatx4 acc[FM][FN] = {};

    auto stage = [&](int t, int b) {
        const int k0 = t * 32;
        #pragma unroll
        for (int i = 0; i < AI; ++i)
            gload_lds16(A + (long)(srow + i * 64) * lda + k0 + sslot * 8,
                        (void*)&As[b][(i * 256 + tid) * 8]);
        #pragma unroll
        for (int i = 0; i < BI; ++i)
            gload_lds16(B + (long)(srow + i * 64) * ldb + k0 + sslot * 8,
                        (void*)&Bs[b][(i * 256 + tid) * 8]);
    };

    stage(0, 0);
    stage(1, 1);
    for (int t = 0; t < nt; ++t) {
        if (t + 2 < nt) {
            stage(t + 2, (t + 2) & 3);
            __builtin_amdgcn_s_waitcnt(wcnt_vm(2 * NL));   // my tile-t loads landed
        } else if (t + 1 < nt) {
            __builtin_amdgcn_s_waitcnt(wcnt_vm(NL));
        } else {
            __builtin_amdgcn_s_waitcnt(wcnt_vm(0));
        }
        __builtin_amdgcn_s_barrier();                      // all waves' tile t landed
        __builtin_amdgcn_sched_barrier(0);

        const int b = t & 3;
        short8 a[FM], bf[FN];
        #pragma unroll
        for (int m = 0; m < FM; ++m)
            a[m] = *(const short8*)&As[b][(wr * (BM / 2) + m * 16 + lrow) * 32 + g * 8];
        #pragma unroll
        for (int n = 0; n < FN; ++n)
            bf[n] = *(const short8*)&Bs[b][(wc * (BN / 2) + n * 16 + lrow) * 32 + g * 8];
        __builtin_amdgcn_s_setprio(1);
        #pragma unroll
        for (int m = 0; m < FM; ++m)
            #pragma unroll
            for (int n = 0; n < FN; ++n)
                acc[m][n] = __builtin_amdgcn_mfma_f32_16x16x32_bf16(
                    a[m], bf[n], acc[m][n], 0, 0, 0);
        __builtin_amdgcn_s_setprio(0);
        __builtin_amdgcn_sched_barrier(0);
    }

    // ---- epilogue: D row = 4g + reg, col = lrow (m89-verified layout) ----
    const int orow = by * BM + wr * (BM / 2);
    const int ocol = bx * BN + wc * (BN / 2);
    if (OMODE == 0) {
        float* C = (float*)Cp + (long)z * sC + (long)half * sP;
        #pragma unroll
        for (int m = 0; m < FM; ++m)
            #pragma unroll
            for (int n = 0; n < FN; ++n)
                #pragma unroll
                for (int r = 0; r < 4; ++r)
                    C[(long)(orow + m * 16 + 4 * g + r) * ldc + ocol + n * 16 + lrow]
                        = acc[m][n][r];
    } else if (OMODE == 1) {
        unsigned short* C = (unsigned short*)Cp + (long)z * sC;
        #pragma unroll
        for (int m = 0; m < FM; ++m)
            #pragma unroll
            for (int n = 0; n < FN; ++n)
                #pragma unroll
                for (int r = 0; r < 4; ++r)
                    C[(long)(orow + m * 16 + 4 * g + r) * ldc + ocol + n * 16 + lrow]
                        = f2b(acc[m][n][r]);
    } else {
        const int* mask = maskp + (long)z * sM;
        float* C = (float*)Cp + (long)z * sC;
        #pragma unroll
        for (int n = 0; n < FN; ++n) {
            int c = ocol + n * 16 + lrow;
            bool masked = (mask[c] != 0);
            #pragma unroll
            for (int m = 0; m < FM; ++m)
                #pragma unroll
                for (int r = 0; r < 4; ++r)
                    C[(long)(orow + m * 16 + 4 * g + r) * ldc + c]
                        = masked ? -INFINITY : acc[m][n][r] * scale;
        }
    }
}

// ---------------------------------------------------------------------------
// Z = P0 + P1 (split-K reduce), float4-wide.
// ---------------------------------------------------------------------------
__global__ __launch_bounds__(256) void reduce_add(
    const float4* __restrict__ P0, const float4* __restrict__ P1,
    float4* __restrict__ Zo)
{
    long i = (long)blockIdx.x * 256 + threadIdx.x;
    float4 a = P0[i], b = P1[i];
    Zo[i] = make_float4(a.x + b.x, a.y + b.y, a.z + b.z, a.w + b.w);
}

// ---------------------------------------------------------------------------
// Weight transpose + convert: W [D][P] fp32 -> WT [P][D] bf16.
// ---------------------------------------------------------------------------
__global__ __launch_bounds__(256) void transpose_w(
    const float* __restrict__ W, unsigned short* __restrict__ WT, int D, int P)
{
    __shared__ float t[32][33];
    const int d0 = blockIdx.x * 32, p0 = blockIdx.y * 32;
    const int tx = threadIdx.x & 31, ty = threadIdx.x >> 5;   // 32x8
    #pragma unroll
    for (int j = 0; j < 4; ++j)
        t[ty + 8 * j][tx] = W[(long)(d0 + ty + 8 * j) * P + p0 + tx];
    __syncthreads();
    #pragma unroll
    for (int j = 0; j < 4; ++j)
        WT[(long)(p0 + ty + 8 * j) * D + d0 + tx] = f2b(t[tx][ty + 8 * j]);
}

// ---------------------------------------------------------------------------
// H [B,L,Dh] fp32 -> Hb [B,L,Dh] bf16 AND HbT [B,Dh,L] bf16, one read.
// ---------------------------------------------------------------------------
__global__ __launch_bounds__(256) void prep_H(
    const float* __restrict__ H, unsigned short* __restrict__ Hb,
    unsigned short* __restrict__ HbT)
{
    __shared__ float tf[32][33];
    const int z = blockIdx.z;
    const int d0 = blockIdx.x * 32, l0 = blockIdx.y * 32;
    const float* Hz = H + (long)z * LKEYS * DH;
    unsigned short* Hbz = Hb + (long)z * LKEYS * DH;
    unsigned short* Tz = HbT + (long)z * DH * LKEYS;
    const int r = threadIdx.x >> 3, c = threadIdx.x & 7;
    float4 v = *(const float4*)&Hz[(long)(l0 + r) * DH + d0 + 4 * c];
    u16x4 w;
    w[0] = f2b(v.x); w[1] = f2b(v.y); w[2] = f2b(v.z); w[3] = f2b(v.w);
    *(u16x4*)&Hbz[(long)(l0 + r) * DH + d0 + 4 * c] = w;
    tf[r][4 * c + 0] = v.x; tf[r][4 * c + 1] = v.y;
    tf[r][4 * c + 2] = v.z; tf[r][4 * c + 3] = v.w;
    __syncthreads();
    u16x4 o;
    o[0] = f2b(tf[4 * c + 0][r]); o[1] = f2b(tf[4 * c + 1][r]);
    o[2] = f2b(tf[4 * c + 2][r]); o[3] = f2b(tf[4 * c + 3][r]);
    *(u16x4*)&Tz[(long)(d0 + r) * LKEYS + l0 + 4 * c] = o;
}

// G fp32 -> Gb bf16, streaming.
__global__ __launch_bounds__(256) void prep_G(
    const float* __restrict__ G, unsigned short* __restrict__ Gb)
{
    long i = ((long)blockIdx.x * 256 + threadIdx.x) * 8;
    float4 a = *(const float4*)&G[i];
    float4 b = *(const float4*)&G[i + 4];
    u16x8 w;
    w[0] = f2b(a.x); w[1] = f2b(a.y); w[2] = f2b(a.z); w[3] = f2b(a.w);
    w[4] = f2b(b.x); w[5] = f2b(b.y); w[6] = f2b(b.z); w[7] = f2b(b.w);
    *(u16x8*)&Gb[i] = w;
}

// ---------------------------------------------------------------------------
// Row softmax, register-cached: 2048 floats/row, 8 elems/thread.
// ---------------------------------------------------------------------------
__global__ __launch_bounds__(256) void softmax_kernel(
    const float* __restrict__ S, unsigned short* __restrict__ Ab)
{
    const float4* row4 = (const float4*)(S + (long)blockIdx.x * LKEYS);
    u16x4* out4 = (u16x4*)(Ab + (long)blockIdx.x * LKEYS);
    const int tid = threadIdx.x;
    __shared__ float red[4];

    float4 v0 = row4[tid], v1 = row4[tid + 256];
    float m = fmaxf(fmaxf(fmaxf(v0.x, v0.y), fmaxf(v0.z, v0.w)),
                    fmaxf(fmaxf(v1.x, v1.y), fmaxf(v1.z, v1.w)));
    #pragma unroll
    for (int off = 32; off > 0; off >>= 1) m = fmaxf(m, __shfl_xor(m, off));
    if ((tid & 63) == 0) red[tid >> 6] = m;
    __syncthreads();
    m = fmaxf(fmaxf(red[0], red[1]), fmaxf(red[2], red[3]));

    float e[8];
    e[0] = __expf(v0.x - m); e[1] = __expf(v0.y - m);
    e[2] = __expf(v0.z - m); e[3] = __expf(v0.w - m);
    e[4] = __expf(v1.x - m); e[5] = __expf(v1.y - m);
    e[6] = __expf(v1.z - m); e[7] = __expf(v1.w - m);
    float s = ((e[0] + e[1]) + (e[2] + e[3])) + ((e[4] + e[5]) + (e[6] + e[7]));
    #pragma unroll
    for (int off = 32; off > 0; off >>= 1) s += __shfl_xor(s, off);
    __syncthreads();
    if ((tid & 63) == 0) red[tid >> 6] = s;
    __syncthreads();
    s = red[0] + red[1] + red[2] + red[3];

    float inv = 1.0f / s;
    u16x4 a0, a1;
    a0[0] = f2b(e[0] * inv); a0[1] = f2b(e[1] * inv);
    a0[2] = f2b(e[2] * inv); a0[3] = f2b(e[3] * inv);
    a1[0] = f2b(e[4] * inv); a1[1] = f2b(e[5] * inv);
    a1[2] = f2b(e[6] * inv); a1[3] = f2b(e[7] * inv);
    out4[tid] = a0; out4[tid + 256] = a1;
}

// ---------------------------------------------------------------------------
extern "C" void kernel_launch(void* const* d_in, const int* in_sizes, int n_in,
                              void* d_out, int out_size, void* d_ws, size_t ws_size,
                              hipStream_t stream)
{
    const float* H    = (const float*)d_in[0];  // [B,L,Dh]
    const float* G    = (const float*)d_in[1];  // [B,T,Dg]
    const int*   mask = (const int*)  d_in[2];  // [B,L]
    const float* Wk   = (const float*)d_in[3];  // [Dh,Dp]
    const float* Wq   = (const float*)d_in[4];  // [Dg,Dp]
    float*       Z    = (float*)d_out;          // [B,T,Dh]

    // Workspace (101.6 MB). u16 offsets:
    // WkT|WqT|Ab|Kb|Qb|Gb|HbT|X  where X = Hb (pre-softmax) then S (logits)
    // then Zp partials (post-softmax) — 33.5 MB region, serially reused.
    unsigned short* WkT = (unsigned short*)d_ws;      // 256*1024
    unsigned short* WqT = WkT + 262144;               // 256*768
    unsigned short* Ab  = WqT + 196608;               // 8*512*2048 bf16
    unsigned short* Kb  = Ab  + 8388608;              // 8*2048*256
    unsigned short* Qb  = Kb  + 4194304;              // 8*512*256
    unsigned short* Gb  = Qb  + 1048576;              // 8*512*768
    unsigned short* HbT = Gb  + 3145728;              // 8*1024*2048
    unsigned short* Hb  = HbT + 16777216;             // 8*2048*1024
    float*          S   = (float*)Hb;                 // overlays Hb
    float*          Zp  = (float*)Hb;                 // overlays S: 2*8*512*1024 f32

    transpose_w<<<dim3(DH / 32, DP / 32), 256, 0, stream>>>(Wk, WkT, DH, DP);
    transpose_w<<<dim3(DG / 32, DP / 32), 256, 0, stream>>>(Wq, WqT, DG, DP);

    prep_G<<<1536, 256, 0, stream>>>(G, Gb);
    prep_H<<<dim3(DH / 32, LKEYS / 32, BATCH), 256, 0, stream>>>(H, Hb, HbT);

    // K = Hb @ WkT^T : M=16384, N=256, K=1024 -> Kb bf16. 512 blocks, 2D swz.
    gemm_bf16_p<128, 64, 1, 1, 1><<<dim3(4, 128, 1), 256, 0, stream>>>(
        Hb, WkT, nullptr, Kb, DH, DH, DH, DP, 0, 0, 0, 0, 0, 1.f);

    // Q = Gb @ WqT^T : M=4096, N=256, K=768 -> Qb bf16. 256 blocks.
    gemm_bf16_p<64, 64, 1, 1, 1><<<dim3(4, 64, 1), 256, 0, stream>>>(
        Gb, WqT, nullptr, Qb, DG, DG, DG, DP, 0, 0, 0, 0, 0, 1.f);

    // logits = scale * Qb @ Kb^T, masked : per batch 512x2048x256 -> S fp32.
    // 3D swz: XCD k owns batch k (Qb+Kb = 1.5 MB, L2-resident). 512 blocks.
    gemm_bf16_p<128, 128, 2, 2, 1><<<dim3(16, 4, BATCH), 256, 0, stream>>>(
        Qb, Kb, mask, S, DP, DP, DP, LKEYS,
        (long)TQ * DP, (long)LKEYS * DP, (long)TQ * LKEYS, (long)LKEYS, 0, SCALE);

    // softmax over L -> bf16 alpha (S dead after this; Zp overlays it)
    softmax_kernel<<<BATCH * TQ, 256, 0, stream>>>(S, Ab);

    // Z partials = Ab @ HbT^T, split-K x2, 128x128 tile. 3D swz: XCD k owns
    // batch k's both halves (Ab[k]+HbT[k] = 6 MB). 512 blocks.
    gemm_bf16_p<128, 128, 0, 2, 2><<<dim3(8, 4, 2 * BATCH), 256, 0, stream>>>(
        Ab, HbT, nullptr, Zp, LKEYS / 2, LKEYS, LKEYS, DH,
        (long)TQ * LKEYS, (long)DH * LKEYS, (long)TQ * DH, 0,
        (long)BATCH * TQ * DH, 1.f);

    // Z = Zp[0] + Zp[1]
    reduce_add<<<(BATCH * TQ * DH / 4) / 256, 256, 0, stream>>>(
        (const float4*)Zp, (const float4*)(Zp + (long)BATCH * TQ * DH),
        (float4*)Z);
}